// Round 1
// baseline (238.365 us; speedup 1.0000x reference)
//
#include <hip/hip_runtime.h>

// Shapes (fixed by the reference):
//   style_encoding (16,512,4,4)  content (16,512,64,64)
//   dw_w (4096,64,2,2)  dw_b (4096)  pw_kn_w (4096,64,1,1) pw_kn_b (4096)
//   pw_bias_w (512,512,1,1) pw_bias_b (512)
//   out (16,512,64,64) f32

#define N_B 16
#define CH  512
#define HW  64
#define SP  4096   // 64*64

// workspace layout (floats)
#define WS_MEAN 0
#define WS_RSTD 8192
#define WS_SD   16384
#define WS_DWK  24576                       // [16][4096][12]  (9 taps + 3 pad)
#define WS_PWK  (24576 + 16*4096*12)        // 811008: [16][4096]
#define WS_PWB  (WS_PWK + 16*4096)          // 876544: [16][512]
// total = 884736 floats = 3.54 MB of d_ws

// ---------------------------------------------------------------- stats ----
__global__ __launch_bounds__(256) void k_stats(const float* __restrict__ content,
                                               const float* __restrict__ style,
                                               float* __restrict__ ws) {
    int bid = blockIdx.x;
    int t = threadIdx.x;
    if (bid < N_B * CH) {
        // per-(n,c) mean / rstd over 4096 elems, unbiased var (ddof=1)
        const float4* row = (const float4*)(content + (size_t)bid * SP);
        float s = 0.f, ss = 0.f;
        for (int k = t; k < SP / 4; k += 256) {
            float4 v = row[k];
            s  += v.x + v.y + v.z + v.w;
            ss += v.x * v.x + v.y * v.y + v.z * v.z + v.w * v.w;
        }
        #pragma unroll
        for (int o = 32; o > 0; o >>= 1) {
            s  += __shfl_down(s, o);
            ss += __shfl_down(ss, o);
        }
        __shared__ float red[8];
        int w = t >> 6;
        if ((t & 63) == 0) { red[w] = s; red[4 + w] = ss; }
        __syncthreads();
        if (t == 0) {
            s  = red[0] + red[1] + red[2] + red[3];
            ss = red[4] + red[5] + red[6] + red[7];
            float mean = s * (1.0f / SP);
            float var  = (ss - s * mean) * (1.0f / (SP - 1));
            ws[WS_MEAN + bid] = mean;
            ws[WS_RSTD + bid] = rsqrtf(var + 1e-5f);
        }
    } else {
        // style spatial mean: 16*512 rows of 16 elems
        int idx = (bid - N_B * CH) * 256 + t;        // 0..8191
        const float* p = style + (size_t)idx * 16;
        float s = 0.f;
        #pragma unroll
        for (int k = 0; k < 16; ++k) s += p[k];
        ws[WS_SD + idx] = s * (1.0f / 16.0f);
    }
}

// ------------------------------------------- depthwise-kernel predictor ----
// dw = relu(conv(style, dw_w, b, groups=8)): in (512,4,4), w (4096,64,2,2)
// -> (4096,3,3) per sample; stored [n][oc][12] (taps 0..8 valid).
__global__ __launch_bounds__(256) void k_dw(const float* __restrict__ style,
                                            const float* __restrict__ dw_w,
                                            const float* __restrict__ dw_b,
                                            float* __restrict__ ws) {
    int n  = blockIdx.x >> 3;
    int sg = blockIdx.x & 7;
    __shared__ float s_tile[64 * 16];   // [ic][4*4]
    int t = threadIdx.x;
    for (int idx = t; idx < 1024; idx += 256)
        s_tile[idx] = style[((size_t)n * CH + sg * 64) * 16 + idx];
    __syncthreads();

    float* dwk = ws + WS_DWK;
    for (int oo = 0; oo < 2; ++oo) {
        int oc = sg * 512 + t + oo * 256;
        float acc[9];
        #pragma unroll
        for (int k = 0; k < 9; ++k) acc[k] = 0.f;
        const float4* wp = (const float4*)(dw_w + (size_t)oc * 256);
        for (int ic = 0; ic < 64; ++ic) {
            float4 w = wp[ic];
            const float* sp = s_tile + ic * 16;
            #pragma unroll
            for (int oy = 0; oy < 3; ++oy)
                #pragma unroll
                for (int ox = 0; ox < 3; ++ox)
                    acc[oy * 3 + ox] += w.x * sp[oy * 4 + ox] + w.y * sp[oy * 4 + ox + 1]
                                      + w.z * sp[(oy + 1) * 4 + ox] + w.w * sp[(oy + 1) * 4 + ox + 1];
        }
        float b = dw_b[oc];
        float* o = dwk + ((size_t)n * 4096 + oc) * 12;
        #pragma unroll
        for (int k = 0; k < 9; ++k) o[k] = fmaxf(acc[k] + b, 0.f);
    }
}

// ----------------------------------- pointwise kernel + bias predictors ----
__global__ __launch_bounds__(256) void k_pw(const float* __restrict__ pw_kn_w,
                                            const float* __restrict__ pw_kn_b,
                                            const float* __restrict__ pw_bias_w,
                                            const float* __restrict__ pw_bias_b,
                                            float* __restrict__ ws) {
    const float* sd = ws + WS_SD;
    __shared__ float s_sd[512];
    int t = threadIdx.x, bid = blockIdx.x;
    if (bid < 256) {
        // pw_kn: 16*4096 outputs, groups=8 (64 in-ch each)
        int n = bid >> 4;
        for (int k = t; k < 512; k += 256) s_sd[k] = sd[n * 512 + k];
        __syncthreads();
        int oc = (bid & 15) * 256 + t;          // 0..4095
        int sg = oc >> 9;
        const float4* wp = (const float4*)(pw_kn_w + (size_t)oc * 64);
        const float* sp = s_sd + sg * 64;
        float a = 0.f;
        #pragma unroll
        for (int k = 0; k < 16; ++k) {
            float4 w = wp[k];
            a += w.x * sp[k * 4] + w.y * sp[k * 4 + 1] + w.z * sp[k * 4 + 2] + w.w * sp[k * 4 + 3];
        }
        ws[WS_PWK + n * 4096 + oc] = fmaxf(a + pw_kn_b[oc], 0.f);
    } else {
        // pw_bias: 16*512 outputs, dense 512-dot
        int idx = (bid - 256) * 256 + t;        // 0..8191
        int n = idx >> 9, oc = idx & 511;
        for (int k = t; k < 512; k += 256) s_sd[k] = sd[n * 512 + k];
        __syncthreads();
        const float4* wp = (const float4*)(pw_bias_w + (size_t)oc * 512);
        float a = 0.f;
        for (int k = 0; k < 128; ++k) {
            float4 w = wp[k];
            a += w.x * s_sd[k * 4] + w.y * s_sd[k * 4 + 1] + w.z * s_sd[k * 4 + 2] + w.w * s_sd[k * 4 + 3];
        }
        ws[WS_PWB + idx] = fmaxf(a + pw_bias_b[oc], 0.f);
    }
}

// ------------------------------------------------------- fused main op ----
// block = (n, group g, 16-row tile ty). 8 channels/group.
// LDS: normalized + reflect-padded tile [8][18][68] (cols 0..65 used).
__global__ __launch_bounds__(256, 3) void k_main(const float* __restrict__ content,
                                                 const float* __restrict__ ws,
                                                 float* __restrict__ out) {
    int bid = blockIdx.x;
    int ty = bid & 3, g = (bid >> 2) & 63, n = bid >> 8;
    __shared__ __align__(16) float cn[8][18][68];
    __shared__ __align__(16) float s_wd[8 * 8 * 12];
    __shared__ float s_wp[64];
    __shared__ float s_wb[8];
    __shared__ float s_ms[16];    // mean[8], rstd[8]

    int t = threadIdx.x;
    // stage weights + stats
    const float* dwk = ws + WS_DWK + ((size_t)n * 4096 + g * 64) * 12;
    for (int k = t; k < 768; k += 256) s_wd[k] = dwk[k];
    if (t < 64) s_wp[t] = ws[WS_PWK + n * 4096 + g * 64 + t];
    if (t < 8) {
        s_wb[t]     = ws[WS_PWB + n * 512 + g * 8 + t];
        s_ms[t]     = ws[WS_MEAN + n * 512 + g * 8 + t];
        s_ms[8 + t] = ws[WS_RSTD + n * 512 + g * 8 + t];
    }
    __syncthreads();

    // stage content tile (normalize + reflect-pad on load)
    int y0 = ty * 16;
    int wv = t >> 6, l = t & 63;
    for (int i = 0; i < 8; ++i) {
        float mean = s_ms[i], rstd = s_ms[8 + i];
        const float* src = content + ((size_t)(n * CH + g * 8 + i)) * SP;
        for (int r = wv; r < 18; r += 4) {
            int gy = y0 + r - 1;
            gy = gy < 0 ? 1 : (gy > 63 ? 62 : gy);
            float v = (src[gy * 64 + l] - mean) * rstd;
            cn[i][r][l + 1] = v;
            if (l == 1)  cn[i][r][0]  = v;   // padded col -1 = col 1
            if (l == 62) cn[i][r][65] = v;   // padded col 64 = col 62
        }
    }
    __syncthreads();

    // compute: each thread owns 4 px (row r_o, cols x0..x0+3)
    int r_o = t >> 4, x0 = (t & 15) << 2;
    float acc[8][4];
    #pragma unroll
    for (int j = 0; j < 8; ++j)
        #pragma unroll
        for (int p = 0; p < 4; ++p) acc[j][p] = 0.f;

    for (int i = 0; i < 8; ++i) {
        float win[3][6];
        #pragma unroll
        for (int ky = 0; ky < 3; ++ky) {
            const float* rp = &cn[i][r_o + ky][x0];
            float4 a = *(const float4*)rp;
            float2 b = *(const float2*)(rp + 4);
            win[ky][0] = a.x; win[ky][1] = a.y; win[ky][2] = a.z;
            win[ky][3] = a.w; win[ky][4] = b.x; win[ky][5] = b.y;
        }
        #pragma unroll
        for (int j = 0; j < 8; ++j) {
            const float* wt = s_wd + (j * 8 + i) * 12;
            float4 w0 = *(const float4*)wt;
            float4 w1 = *(const float4*)(wt + 4);
            float  w8 = wt[8];
            #pragma unroll
            for (int p = 0; p < 4; ++p)
                acc[j][p] += w0.x * win[0][p] + w0.y * win[0][p + 1] + w0.z * win[0][p + 2]
                           + w0.w * win[1][p] + w1.x * win[1][p + 1] + w1.y * win[1][p + 2]
                           + w1.z * win[2][p] + w1.w * win[2][p + 1] + w8  * win[2][p + 2];
        }
    }

    // pointwise + bias + leaky(0.01) + cn add + store
    size_t obase = ((size_t)(n * CH + g * 8) * 64 + (y0 + r_o)) * 64 + x0;
    #pragma unroll
    for (int j2 = 0; j2 < 8; ++j2) {
        float4 o;
        float* op = &o.x;
        #pragma unroll
        for (int p = 0; p < 4; ++p) {
            float a = s_wb[j2];
            #pragma unroll
            for (int j = 0; j < 8; ++j) a += acc[j][p] * s_wp[j2 * 8 + j];
            a = a > 0.f ? a : 0.01f * a;
            op[p] = a + cn[j2][r_o + 1][x0 + 1 + p];
        }
        *(float4*)(out + obase + (size_t)j2 * SP) = o;
    }
}

extern "C" void kernel_launch(void* const* d_in, const int* in_sizes, int n_in,
                              void* d_out, int out_size, void* d_ws, size_t ws_size,
                              hipStream_t stream) {
    const float* style     = (const float*)d_in[0];
    const float* content   = (const float*)d_in[1];
    const float* dw_w      = (const float*)d_in[2];
    const float* dw_b      = (const float*)d_in[3];
    const float* pw_kn_w   = (const float*)d_in[4];
    const float* pw_kn_b   = (const float*)d_in[5];
    const float* pw_bias_w = (const float*)d_in[6];
    const float* pw_bias_b = (const float*)d_in[7];
    float* out = (float*)d_out;
    float* ws  = (float*)d_ws;

    k_stats<<<dim3(N_B * CH + 32), dim3(256), 0, stream>>>(content, style, ws);
    k_dw   <<<dim3(128),           dim3(256), 0, stream>>>(style, dw_w, dw_b, ws);
    k_pw   <<<dim3(288),           dim3(256), 0, stream>>>(pw_kn_w, pw_kn_b, pw_bias_w, pw_bias_b, ws);
    k_main <<<dim3(4096),          dim3(256), 0, stream>>>(content, ws, out);
}

// Round 2
// 168.388 us; speedup vs baseline: 1.4156x; 1.4156x over previous
//
#include <hip/hip_runtime.h>

// Shapes (fixed by the reference):
//   style_encoding (16,512,4,4)  content (16,512,64,64)
//   dw_w (4096,64,2,2)  dw_b (4096)  pw_kn_w (4096,64,1,1) pw_kn_b (4096)
//   pw_bias_w (512,512,1,1) pw_bias_b (512)
//   out (16,512,64,64) f32

#define N_B 16
#define CH  512
#define HW  64
#define SP  4096   // 64*64

// workspace layout (floats)
#define WS_MEAN 0
#define WS_RSTD 8192
#define WS_SD   16384
#define WS_DWK  24576                       // [16][4096][12]  (9 taps + 3 pad)
#define WS_PWK  (24576 + 16*4096*12)        // 811008: [16][4096]
#define WS_PWB  (WS_PWK + 16*4096)          // 876544: [16][512]

// round-nearest f32 -> bf16 bits (half-up; bias 2^-10, inputs are bounded)
__device__ __forceinline__ unsigned bf16b(float x) {
    union { float f; unsigned u; } v; v.f = x;
    return (v.u + 0x8000u) >> 16;
}
__device__ __forceinline__ float bflo(unsigned u) {
    union { unsigned u; float f; } v; v.u = u << 16; return v.f;
}
__device__ __forceinline__ float bfhi(unsigned u) {
    union { unsigned u; float f; } v; v.u = u & 0xFFFF0000u; return v.f;
}

// ---------------------------------------------------------------- stats ----
__global__ __launch_bounds__(256) void k_stats(const float* __restrict__ content,
                                               const float* __restrict__ style,
                                               float* __restrict__ ws) {
    int bid = blockIdx.x;
    int t = threadIdx.x;
    if (bid < N_B * CH) {
        const float4* row = (const float4*)(content + (size_t)bid * SP);
        float s = 0.f, ss = 0.f;
        for (int k = t; k < SP / 4; k += 256) {
            float4 v = row[k];
            s  += v.x + v.y + v.z + v.w;
            ss += v.x * v.x + v.y * v.y + v.z * v.z + v.w * v.w;
        }
        #pragma unroll
        for (int o = 32; o > 0; o >>= 1) {
            s  += __shfl_down(s, o);
            ss += __shfl_down(ss, o);
        }
        __shared__ float red[8];
        int w = t >> 6;
        if ((t & 63) == 0) { red[w] = s; red[4 + w] = ss; }
        __syncthreads();
        if (t == 0) {
            s  = red[0] + red[1] + red[2] + red[3];
            ss = red[4] + red[5] + red[6] + red[7];
            float mean = s * (1.0f / SP);
            float var  = (ss - s * mean) * (1.0f / (SP - 1));
            ws[WS_MEAN + bid] = mean;
            ws[WS_RSTD + bid] = rsqrtf(var + 1e-5f);
        }
    } else {
        int idx = (bid - N_B * CH) * 256 + t;        // 0..8191
        const float* p = style + (size_t)idx * 16;
        float s = 0.f;
        #pragma unroll
        for (int k = 0; k < 16; ++k) s += p[k];
        ws[WS_SD + idx] = s * (1.0f / 16.0f);
    }
}

// ------------------------------------------- depthwise-kernel predictor ----
__global__ __launch_bounds__(256) void k_dw(const float* __restrict__ style,
                                            const float* __restrict__ dw_w,
                                            const float* __restrict__ dw_b,
                                            float* __restrict__ ws) {
    int n    = blockIdx.x >> 4;
    int rem  = blockIdx.x & 15;
    int sg   = rem >> 1;
    int half = rem & 1;
    __shared__ float s_tile[64 * 16];   // [ic][4*4]
    int t = threadIdx.x;
    for (int idx = t; idx < 1024; idx += 256)
        s_tile[idx] = style[((size_t)n * CH + sg * 64) * 16 + idx];
    __syncthreads();

    int oc = sg * 512 + half * 256 + t;
    float acc[9];
    #pragma unroll
    for (int k = 0; k < 9; ++k) acc[k] = 0.f;
    const float4* wp = (const float4*)(dw_w + (size_t)oc * 256);
    for (int ic = 0; ic < 64; ++ic) {
        float4 w = wp[ic];
        const float* sp = s_tile + ic * 16;
        #pragma unroll
        for (int oy = 0; oy < 3; ++oy)
            #pragma unroll
            for (int ox = 0; ox < 3; ++ox)
                acc[oy * 3 + ox] += w.x * sp[oy * 4 + ox] + w.y * sp[oy * 4 + ox + 1]
                                  + w.z * sp[(oy + 1) * 4 + ox] + w.w * sp[(oy + 1) * 4 + ox + 1];
    }
    float b = dw_b[oc];
    float* o = ws + WS_DWK + ((size_t)n * 4096 + oc) * 12;
    #pragma unroll
    for (int k = 0; k < 9; ++k) o[k] = fmaxf(acc[k] + b, 0.f);
}

// ----------------------------------- pointwise kernel + bias predictors ----
__global__ __launch_bounds__(256) void k_pw(const float* __restrict__ pw_kn_w,
                                            const float* __restrict__ pw_kn_b,
                                            const float* __restrict__ pw_bias_w,
                                            const float* __restrict__ pw_bias_b,
                                            float* __restrict__ ws) {
    const float* sd = ws + WS_SD;
    __shared__ float s_sd[512];
    int t = threadIdx.x, bid = blockIdx.x;
    if (bid < 256) {
        int n = bid >> 4;
        for (int k = t; k < 512; k += 256) s_sd[k] = sd[n * 512 + k];
        __syncthreads();
        int oc = (bid & 15) * 256 + t;          // 0..4095
        int sg = oc >> 9;
        const float4* wp = (const float4*)(pw_kn_w + (size_t)oc * 64);
        const float* sp = s_sd + sg * 64;
        float a = 0.f;
        #pragma unroll
        for (int k = 0; k < 16; ++k) {
            float4 w = wp[k];
            a += w.x * sp[k * 4] + w.y * sp[k * 4 + 1] + w.z * sp[k * 4 + 2] + w.w * sp[k * 4 + 3];
        }
        ws[WS_PWK + n * 4096 + oc] = fmaxf(a + pw_kn_b[oc], 0.f);
    } else {
        int idx = (bid - 256) * 256 + t;        // 0..8191
        int n = idx >> 9, oc = idx & 511;
        for (int k = t; k < 512; k += 256) s_sd[k] = sd[n * 512 + k];
        __syncthreads();
        const float4* wp = (const float4*)(pw_bias_w + (size_t)oc * 512);
        float a = 0.f;
        for (int k = 0; k < 128; ++k) {
            float4 w = wp[k];
            a += w.x * s_sd[k * 4] + w.y * s_sd[k * 4 + 1] + w.z * s_sd[k * 4 + 2] + w.w * s_sd[k * 4 + 3];
        }
        ws[WS_PWB + idx] = fmaxf(a + pw_bias_b[oc], 0.f);
    }
}

// ------------------------------------------------------- fused main op ----
// block = (n, group g, 16-row tile ty). 8 channels/group.
// LDS tile: bf16, position p stores column p-1 (p=0..65), row stride 72.
// col c -> position c+1; reflect: position 0 = col 1, position 65 = col 62.
#define TST 72
__global__ __launch_bounds__(256, 5) void k_main(const float* __restrict__ content,
                                                 const float* __restrict__ ws,
                                                 float* __restrict__ out) {
    int bid = blockIdx.x;
    int ty = bid & 3, g = (bid >> 2) & 63, n = bid >> 8;
    __shared__ __align__(16) unsigned short cn[8][18][TST];
    __shared__ __align__(16) float s_wd[8 * 8 * 12];
    __shared__ float s_wp[64];
    __shared__ float s_wb[8];
    __shared__ float s_ms[16];    // mean[8], rstd[8]

    int t = threadIdx.x;
    const float* dwk = ws + WS_DWK + ((size_t)n * 4096 + g * 64) * 12;
    for (int k = t; k < 768; k += 256) s_wd[k] = dwk[k];
    if (t < 64) s_wp[t] = ws[WS_PWK + n * 4096 + g * 64 + t];
    if (t < 8) {
        s_wb[t]     = ws[WS_PWB + n * 512 + g * 8 + t];
        s_ms[t]     = ws[WS_MEAN + n * 512 + g * 8 + t];
        s_ms[8 + t] = ws[WS_RSTD + n * 512 + g * 8 + t];
    }
    __syncthreads();

    // ---- stage: 144 (ch,row) segments, 16 lanes each: one float4 -> b64 ----
    int y0 = ty * 16;
    int q = t & 15, grp = t >> 4;
    const float* cbase = content + ((size_t)(n * CH + g * 8)) * SP;
    #pragma unroll 3
    for (int cc = 0; cc < 9; ++cc) {
        int rowid = cc * 16 + grp;            // 0..143
        int i = rowid / 18, r = rowid - i * 18;
        float mean = s_ms[i], rstd = s_ms[8 + i];
        int gy = y0 + r - 1;
        gy = gy < 0 ? 1 : (gy > 63 ? 62 : gy);
        float4 v = *(const float4*)(cbase + (size_t)i * SP + gy * 64 + 4 * q);
        v.x = (v.x - mean) * rstd; v.y = (v.y - mean) * rstd;
        v.z = (v.z - mean) * rstd; v.w = (v.w - mean) * rstd;
        unsigned u0 = bf16b(v.x) | (bf16b(v.y) << 16);
        unsigned u1 = bf16b(v.z) | (bf16b(v.w) << 16);
        unsigned pu1 = __shfl_up(u1, 1);
        if (q == 0) pu1 = u0;                  // col -1 = reflect(col 1) = hi16(u0)
        uint2 o;
        o.x = (pu1 >> 16) | (u0 << 16);        // positions 4q,4q+1 = cols 4q-1,4q
        o.y = (u0 >> 16) | (u1 << 16);         // positions 4q+2,4q+3 = cols 4q+1,4q+2
        *(uint2*)&cn[i][r][4 * q] = o;
        if (q == 15)                           // positions 64,65 = cols 63, 62(reflect)
            *(unsigned*)&cn[i][r][64] = (u1 >> 16) | (u1 << 16);
    }
    __syncthreads();

    // ---- compute: thread owns 4 px (row r_o, cols x0..x0+3) ----
    int r_o = t >> 4, k16 = t & 15, x0 = k16 << 2;
    float acc[8][4];
    #pragma unroll
    for (int j = 0; j < 8; ++j)
        #pragma unroll
        for (int p = 0; p < 4; ++p) acc[j][p] = 0.f;

    for (int i = 0; i < 8; ++i) {
        float win[3][6];                        // cols x0-1 .. x0+4
        #pragma unroll
        for (int ky = 0; ky < 3; ++ky) {
            const unsigned short* rp = &cn[i][r_o + ky][0];
            uint2 a = *(const uint2*)(rp + 4 * k16);          // positions x0..x0+3
            unsigned b = *(const unsigned*)(rp + 4 * k16 + 4); // positions x0+4,x0+5
            win[ky][0] = bflo(a.x); win[ky][1] = bfhi(a.x);
            win[ky][2] = bflo(a.y); win[ky][3] = bfhi(a.y);
            win[ky][4] = bflo(b);   win[ky][5] = bfhi(b);
        }
        #pragma unroll
        for (int j = 0; j < 8; ++j) {
            const float* wt = s_wd + (j * 8 + i) * 12;
            float4 w0 = *(const float4*)wt;
            float4 w1 = *(const float4*)(wt + 4);
            float  w8 = wt[8];
            #pragma unroll
            for (int p = 0; p < 4; ++p)
                acc[j][p] += w0.x * win[0][p] + w0.y * win[0][p + 1] + w0.z * win[0][p + 2]
                           + w0.w * win[1][p] + w1.x * win[1][p + 1] + w1.y * win[1][p + 2]
                           + w1.z * win[2][p] + w1.w * win[2][p + 1] + w8  * win[2][p + 2];
        }
    }

    // ---- pointwise + bias + leaky(0.01) + cn add + store ----
    size_t obase = ((size_t)(n * CH + g * 8) * 64 + (y0 + r_o)) * 64 + x0;
    #pragma unroll
    for (int j2 = 0; j2 < 8; ++j2) {
        const unsigned short* rp = &cn[j2][r_o + 1][0];
        uint2 a = *(const uint2*)(rp + 4 * k16);           // positions x0..x0+3 = cols x0-1..x0+2
        unsigned bb = *(const unsigned*)(rp + 4 * k16 + 4); // position x0+4 = col x0+3
        float c0 = bfhi(a.x), c1 = bflo(a.y), c2 = bfhi(a.y), c3 = bflo(bb);
        float4 o;
        float* op = &o.x;
        float cv[4] = {c0, c1, c2, c3};
        #pragma unroll
        for (int p = 0; p < 4; ++p) {
            float a2 = s_wb[j2];
            #pragma unroll
            for (int j = 0; j < 8; ++j) a2 += acc[j][p] * s_wp[j2 * 8 + j];
            a2 = a2 > 0.f ? a2 : 0.01f * a2;
            op[p] = a2 + cv[p];
        }
        *(float4*)(out + obase + (size_t)j2 * SP) = o;
    }
}

extern "C" void kernel_launch(void* const* d_in, const int* in_sizes, int n_in,
                              void* d_out, int out_size, void* d_ws, size_t ws_size,
                              hipStream_t stream) {
    const float* style     = (const float*)d_in[0];
    const float* content   = (const float*)d_in[1];
    const float* dw_w      = (const float*)d_in[2];
    const float* dw_b      = (const float*)d_in[3];
    const float* pw_kn_w   = (const float*)d_in[4];
    const float* pw_kn_b   = (const float*)d_in[5];
    const float* pw_bias_w = (const float*)d_in[6];
    const float* pw_bias_b = (const float*)d_in[7];
    float* out = (float*)d_out;
    float* ws  = (float*)d_ws;

    k_stats<<<dim3(N_B * CH + 32), dim3(256), 0, stream>>>(content, style, ws);
    k_dw   <<<dim3(256),           dim3(256), 0, stream>>>(style, dw_w, dw_b, ws);
    k_pw   <<<dim3(288),           dim3(256), 0, stream>>>(pw_kn_w, pw_kn_b, pw_bias_w, pw_bias_b, ws);
    k_main <<<dim3(4096),          dim3(256), 0, stream>>>(content, ws, out);
}

// Round 4
// 116.889 us; speedup vs baseline: 2.0392x; 1.4406x over previous
//
#include <hip/hip_runtime.h>

// Shapes (fixed by the reference):
//   style_encoding (16,512,4,4)  content (16,512,64,64)
//   dw_w (4096,64,2,2)  dw_b (4096)  pw_kn_w (4096,64,1,1) pw_kn_b (4096)
//   pw_bias_w (512,512,1,1) pw_bias_b (512)
//   out (16,512,64,64) f32

#define N_B 16
#define CH  512
#define SP  4096   // 64*64

// workspace layout (floats)
#define WS_MEAN 0
#define WS_RSTD 8192
#define WS_SD   16384
#define WS_PWB  24576                 // [16][512]
#define WS_W    32768                 // [16][64][512 dwords] fused f16-packed weights
// total 557056 floats = 2.23 MB

typedef float f32x4 __attribute__((ext_vector_type(4)));

__device__ __forceinline__ unsigned pk16(float x, float y) {
    __fp16 h2[2] = { (__fp16)0, (__fp16)0 };
    auto h = __builtin_amdgcn_cvt_pkrtz(x, y);
    unsigned u; __builtin_memcpy(&u, &h, 4); return u;
    (void)h2;
}
__device__ __forceinline__ float f16lo(unsigned u) {
    unsigned short s = (unsigned short)u; _Float16 h;
    __builtin_memcpy(&h, &s, 2); return (float)h;
}
__device__ __forceinline__ float f16hi(unsigned u) {
    unsigned short s = (unsigned short)(u >> 16); _Float16 h;
    __builtin_memcpy(&h, &s, 2); return (float)h;
}
// acc += a(f16x2) . b(f16x2), f32 accumulate
__device__ __forceinline__ float dot2(unsigned a, unsigned b, float c) {
    asm("v_dot2_f32_f16 %0, %1, %2, %0" : "+v"(c) : "v"(a), "v"(b));
    return c;
}

// ---------------------------------------------------------------- stats ----
__global__ __launch_bounds__(256) void k_stats(const float* __restrict__ content,
                                               const float* __restrict__ style,
                                               float* __restrict__ ws) {
    int bid = blockIdx.x;
    int t = threadIdx.x;
    if (bid < N_B * CH) {
        const float4* row = (const float4*)(content + (size_t)bid * SP);
        float s = 0.f, ss = 0.f;
        for (int k = t; k < SP / 4; k += 256) {
            float4 v = row[k];
            s  += v.x + v.y + v.z + v.w;
            ss += v.x * v.x + v.y * v.y + v.z * v.z + v.w * v.w;
        }
        #pragma unroll
        for (int o = 32; o > 0; o >>= 1) {
            s  += __shfl_down(s, o);
            ss += __shfl_down(ss, o);
        }
        __shared__ float red[8];
        int w = t >> 6;
        if ((t & 63) == 0) { red[w] = s; red[4 + w] = ss; }
        __syncthreads();
        if (t == 0) {
            s  = red[0] + red[1] + red[2] + red[3];
            ss = red[4] + red[5] + red[6] + red[7];
            float mean = s * (1.0f / SP);
            float var  = (ss - s * mean) * (1.0f / (SP - 1));
            ws[WS_MEAN + bid] = mean;
            ws[WS_RSTD + bid] = rsqrtf(var + 1e-5f);
        }
    } else {
        int idx = (bid - N_B * CH) * 256 + t;        // 0..8191
        const float* p = style + (size_t)idx * 16;
        float s = 0.f;
        #pragma unroll
        for (int k = 0; k < 16; ++k) s += p[k];
        ws[WS_SD + idx] = s * (1.0f / 16.0f);
    }
}

// --------------------------- fused predictor: dw + pw_kn + pw_bias + fold ----
// block = (n, g). Produces per-(n,g): pwb[8] and packed fused weights
// W[j2][i]: d0=(k00,k01) d1=(k10,k11) d2=(k20,k21) d3=(k02,k12) d4=k22(f32), 8 dwords.
__global__ __launch_bounds__(256) void k_pred(const float* __restrict__ style,
                                              const float* __restrict__ dw_w,
                                              const float* __restrict__ dw_b,
                                              const float* __restrict__ pw_kn_w,
                                              const float* __restrict__ pw_kn_b,
                                              const float* __restrict__ pw_bias_w,
                                              const float* __restrict__ pw_bias_b,
                                              float* __restrict__ ws) {
    int n = blockIdx.x >> 6, g = blockIdx.x & 63, sg = g >> 3;
    __shared__ float s_st[64 * 16];
    __shared__ float s_sd[512];
    __shared__ float s_dwk[64 * 9];
    __shared__ float s_pwk[64];
    __shared__ float s_W[64 * 9];
    int t = threadIdx.x;

    for (int idx = t; idx < 1024; idx += 256)
        s_st[idx] = style[((size_t)n * CH + sg * 64) * 16 + idx];
    for (int idx = t; idx < 512; idx += 256)
        s_sd[idx] = ws[WS_SD + n * 512 + idx];
    __syncthreads();

    if (t < 192) {
        // depthwise predictor: oc_l = t&63, row ky = t>>6, 3 taps each
        int oc_l = t & 63, ky = t >> 6;
        int oc = g * 64 + oc_l;
        const float4* wp = (const float4*)(dw_w + (size_t)oc * 256);
        float a0 = 0.f, a1 = 0.f, a2 = 0.f;
        for (int ic = 0; ic < 64; ++ic) {
            float4 w = wp[ic];
            const float* sp = s_st + ic * 16 + ky * 4;
            a0 += w.x * sp[0] + w.y * sp[1] + w.z * sp[4] + w.w * sp[5];
            a1 += w.x * sp[1] + w.y * sp[2] + w.z * sp[5] + w.w * sp[6];
            a2 += w.x * sp[2] + w.y * sp[3] + w.z * sp[6] + w.w * sp[7];
        }
        float b = dw_b[oc];
        s_dwk[oc_l * 9 + ky * 3 + 0] = fmaxf(a0 + b, 0.f);
        s_dwk[oc_l * 9 + ky * 3 + 1] = fmaxf(a1 + b, 0.f);
        s_dwk[oc_l * 9 + ky * 3 + 2] = fmaxf(a2 + b, 0.f);
    } else {
        int L = t - 192;                       // lane 0..63 of wave 3
        // pointwise-kernel predictor (one 64-dot per L)
        {
            const float4* wp = (const float4*)(pw_kn_w + (size_t)(g * 64 + L) * 64);
            const float* sp = s_sd + sg * 64;
            float a = 0.f;
            #pragma unroll
            for (int k = 0; k < 16; ++k) {
                float4 w = wp[k];
                a += w.x * sp[k * 4] + w.y * sp[k * 4 + 1] + w.z * sp[k * 4 + 2] + w.w * sp[k * 4 + 3];
            }
            s_pwk[L] = fmaxf(a + pw_kn_b[g * 64 + L], 0.f);
        }
        // pointwise-bias predictor: 8 outputs x 8 lanes (64-chunk each)
        {
            int j2 = L >> 3, ch = L & 7;
            int c2 = g * 8 + j2;
            const float4* bp = (const float4*)(pw_bias_w + (size_t)c2 * 512 + ch * 64);
            const float* sq = s_sd + ch * 64;
            float s = 0.f;
            #pragma unroll
            for (int k = 0; k < 16; ++k) {
                float4 w = bp[k];
                s += w.x * sq[k * 4] + w.y * sq[k * 4 + 1] + w.z * sq[k * 4 + 2] + w.w * sq[k * 4 + 3];
            }
            s += __shfl_down(s, 4);
            s += __shfl_down(s, 2);
            s += __shfl_down(s, 1);
            if (ch == 0) ws[WS_PWB + n * 512 + c2] = fmaxf(s + pw_bias_b[c2], 0.f);
        }
    }
    __syncthreads();

    // fold pointwise into depthwise: W[j2][i][tap] = sum_j pwk[j2*8+j]*dwk[(j*8+i)][tap]
    for (int job = t; job < 576; job += 256) {
        int tap = job % 9, ji = job / 9;
        int j2 = ji >> 3, i = ji & 7;
        float a = 0.f;
        #pragma unroll
        for (int j = 0; j < 8; ++j)
            a += s_pwk[j2 * 8 + j] * s_dwk[(j * 8 + i) * 9 + tap];
        s_W[ji * 9 + tap] = a;
    }
    __syncthreads();

    // pack to f16 pairs
    unsigned* wout = (unsigned*)(ws + WS_W) + (size_t)(n * 64 + g) * 512;
    for (int job = t; job < 512; job += 256) {
        int ji = job >> 3, d2 = job & 7;
        const float* Wp = s_W + ji * 9;
        unsigned v = 0;
        if      (d2 == 0) v = pk16(Wp[0], Wp[1]);
        else if (d2 == 1) v = pk16(Wp[3], Wp[4]);
        else if (d2 == 2) v = pk16(Wp[6], Wp[7]);
        else if (d2 == 3) v = pk16(Wp[2], Wp[5]);
        else if (d2 == 4) { float f = Wp[8]; __builtin_memcpy(&v, &f, 4); }
        wout[job] = v;
    }
}

// ------------------------------------------------------- fused main op ----
// block = (n, group g, 16-row tile ty). LDS tile f16: position p = col p-1,
// row stride 72 (p=0..65 used). Reflect: pos0=col1, pos65=col62.
#define TST 72
__global__ __launch_bounds__(256, 5) void k_main(const float* __restrict__ content,
                                                 const float* __restrict__ ws,
                                                 float* __restrict__ out) {
    int bid = blockIdx.x;
    int ty = bid & 3, g = (bid >> 2) & 63, n = bid >> 8;
    __shared__ __align__(16) unsigned short cn[8][18][TST];
    __shared__ __align__(16) unsigned s_w[512];
    __shared__ float s_wb[8];
    __shared__ float s_ms[16];

    int t = threadIdx.x;
    {
        const float4* wsrc = (const float4*)(ws + WS_W) + (size_t)(n * 64 + g) * 128;
        if (t < 128) ((float4*)s_w)[t] = wsrc[t];
        if (t < 8) {
            s_wb[t]     = ws[WS_PWB + n * 512 + g * 8 + t];
            s_ms[t]     = ws[WS_MEAN + n * 512 + g * 8 + t];
            s_ms[8 + t] = ws[WS_RSTD + n * 512 + g * 8 + t];
        }
    }
    __syncthreads();

    // ---- stage: 144 (ch,row) segments, 16 lanes each ----
    int y0 = ty * 16;
    int q = t & 15, grp = t >> 4;
    const float* cbase = content + ((size_t)(n * CH + g * 8)) * SP;
    #pragma unroll 3
    for (int cc = 0; cc < 9; ++cc) {
        int rowid = cc * 16 + grp;            // 0..143
        int i = rowid / 18, r = rowid - i * 18;
        float sA = s_ms[8 + i];               // rstd
        float sB = -s_ms[i] * sA;             // -mean*rstd
        int gy = y0 + r - 1;
        gy = gy < 0 ? 1 : (gy > 63 ? 62 : gy);
        float4 v = *(const float4*)(cbase + (size_t)i * SP + gy * 64 + 4 * q);
        unsigned u0 = pk16(fmaf(v.x, sA, sB), fmaf(v.y, sA, sB));
        unsigned u1 = pk16(fmaf(v.z, sA, sB), fmaf(v.w, sA, sB));
        unsigned pu1 = __shfl_up(u1, 1);
        if (q == 0) pu1 = u0;                  // pos0 = reflect(col1)
        uint2 o;
        o.x = (pu1 >> 16) | (u0 << 16);        // positions 4q,4q+1
        o.y = (u0 >> 16) | (u1 << 16);         // positions 4q+2,4q+3
        *(uint2*)&cn[i][r][4 * q] = o;
        if (q == 15)                           // positions 64,65 = cols 63,62
            *(unsigned*)&cn[i][r][64] = (u1 >> 16) | (u1 << 16);
    }
    __syncthreads();

    // ---- compute: thread owns 4 px (row r_o, cols x0..x0+3) ----
    int r_o = t >> 4, k16 = t & 15, x0 = k16 << 2;
    float acc[8][4];
    #pragma unroll
    for (int j = 0; j < 8; ++j)
        #pragma unroll
        for (int p = 0; p < 4; ++p) acc[j][p] = 0.f;

    for (int i = 0; i < 8; ++i) {
        unsigned R0[3], R1[3], R2[3];
        #pragma unroll
        for (int ky = 0; ky < 3; ++ky) {
            const unsigned short* rp = &cn[i][r_o + ky][4 * k16];
            uint2 a = *(const uint2*)rp;               // positions x0..x0+3
            unsigned b = *(const unsigned*)(rp + 4);   // positions x0+4,x0+5
            R0[ky] = a.x; R1[ky] = a.y; R2[ky] = b;
        }
        unsigned pr[3][4];
        #pragma unroll
        for (int ky = 0; ky < 3; ++ky) {
            pr[ky][0] = R0[ky];
            pr[ky][1] = __builtin_amdgcn_alignbit(R1[ky], R0[ky], 16);
            pr[ky][2] = R1[ky];
            pr[ky][3] = __builtin_amdgcn_alignbit(R2[ky], R1[ky], 16);
        }
        unsigned cp[4];
        cp[0] = __builtin_amdgcn_perm(R1[1], R1[0], 0x05040100u);  // (lo,lo)
        cp[1] = __builtin_amdgcn_perm(R1[1], R1[0], 0x07060302u);  // (hi,hi)
        cp[2] = __builtin_amdgcn_perm(R2[1], R2[0], 0x05040100u);
        cp[3] = __builtin_amdgcn_perm(R2[1], R2[0], 0x07060302u);
        float sf[4] = { f16lo(R1[2]), f16hi(R1[2]), f16lo(R2[2]), f16hi(R2[2]) };
        #pragma unroll
        for (int j2 = 0; j2 < 8; ++j2) {
            const unsigned* wb = &s_w[(j2 * 8 + i) * 8];
            uint4 d = *(const uint4*)wb;
            float k22 = ((const float*)wb)[4];
            #pragma unroll
            for (int p = 0; p < 4; ++p) {
                float a = acc[j2][p];
                a = dot2(d.x, pr[0][p], a);
                a = dot2(d.y, pr[1][p], a);
                a = dot2(d.z, pr[2][p], a);
                a = dot2(d.w, cp[p], a);
                acc[j2][p] = fmaf(k22, sf[p], a);
            }
        }
    }

    // ---- bias + leaky(0.01) + cn add + NT store ----
    size_t obase = ((size_t)(n * CH + g * 8) * 64 + (y0 + r_o)) * 64 + x0;
    #pragma unroll
    for (int j2 = 0; j2 < 8; ++j2) {
        const unsigned short* rp = &cn[j2][r_o + 1][4 * k16];
        uint2 a = *(const uint2*)rp;
        unsigned b = *(const unsigned*)(rp + 4);
        float cv[4] = { f16hi(a.x), f16lo(a.y), f16hi(a.y), f16lo(b) };
        float bias = s_wb[j2];
        f32x4 o;
        #pragma unroll
        for (int p = 0; p < 4; ++p) {
            float v = acc[j2][p] + bias;
            v = v > 0.f ? v : 0.01f * v;
            o[p] = v + cv[p];
        }
        __builtin_nontemporal_store(o, (f32x4*)(out + obase + (size_t)j2 * SP));
    }
}

extern "C" void kernel_launch(void* const* d_in, const int* in_sizes, int n_in,
                              void* d_out, int out_size, void* d_ws, size_t ws_size,
                              hipStream_t stream) {
    const float* style     = (const float*)d_in[0];
    const float* content   = (const float*)d_in[1];
    const float* dw_w      = (const float*)d_in[2];
    const float* dw_b      = (const float*)d_in[3];
    const float* pw_kn_w   = (const float*)d_in[4];
    const float* pw_kn_b   = (const float*)d_in[5];
    const float* pw_bias_w = (const float*)d_in[6];
    const float* pw_bias_b = (const float*)d_in[7];
    float* out = (float*)d_out;
    float* ws  = (float*)d_ws;

    k_stats<<<dim3(N_B * CH + 32), dim3(256), 0, stream>>>(content, style, ws);
    k_pred <<<dim3(1024),          dim3(256), 0, stream>>>(style, dw_w, dw_b, pw_kn_w,
                                                           pw_kn_b, pw_bias_w, pw_bias_b, ws);
    k_main <<<dim3(4096),          dim3(256), 0, stream>>>(content, ws, out);
}

// Round 10
// 116.349 us; speedup vs baseline: 2.0487x; 1.0046x over previous
//
#include <hip/hip_runtime.h>

// Shapes (fixed by the reference):
//   style_encoding (16,512,4,4)  content (16,512,64,64)
//   dw_w (4096,64,2,2)  dw_b (4096)  pw_kn_w (4096,64,1,1) pw_kn_b (4096)
//   pw_bias_w (512,512,1,1) pw_bias_b (512)
//   out (16,512,64,64) f32

#define N_B 16
#define CH  512
#define SP  4096   // 64*64

// workspace layout (floats)
#define WS_MEAN 0
#define WS_RSTD 8192
#define WS_SD   16384
#define WS_PWB  24576                 // [16][512]
#define WS_W    32768                 // [16][64][512 dwords] fused f16-packed weights

typedef float f32x4 __attribute__((ext_vector_type(4)));

__device__ __forceinline__ unsigned pk16(float x, float y) {
    auto h = __builtin_amdgcn_cvt_pkrtz(x, y);
    unsigned u; __builtin_memcpy(&u, &h, 4); return u;
}
__device__ __forceinline__ float f16lo(unsigned u) {
    unsigned short s = (unsigned short)u; _Float16 h;
    __builtin_memcpy(&h, &s, 2); return (float)h;
}
__device__ __forceinline__ float f16hi(unsigned u) {
    unsigned short s = (unsigned short)(u >> 16); _Float16 h;
    __builtin_memcpy(&h, &s, 2); return (float)h;
}
// acc += a(f16x2) . b(f16x2), f32 accumulate
__device__ __forceinline__ float dot2(unsigned a, unsigned b, float c) {
    asm("v_dot2_f32_f16 %0, %1, %2, %0" : "+v"(c) : "v"(a), "v"(b));
    return c;
}

// ---------------------------------------------------------------- stats ----
__global__ __launch_bounds__(256) void k_stats(const float* __restrict__ content,
                                               const float* __restrict__ style,
                                               float* __restrict__ ws) {
    int bid = blockIdx.x;
    int t = threadIdx.x;
    if (bid < N_B * CH) {
        const float4* row = (const float4*)(content + (size_t)bid * SP);
        float s = 0.f, ss = 0.f;
        for (int k = t; k < SP / 4; k += 256) {
            float4 v = row[k];
            s  += v.x + v.y + v.z + v.w;
            ss += v.x * v.x + v.y * v.y + v.z * v.z + v.w * v.w;
        }
        #pragma unroll
        for (int o = 32; o > 0; o >>= 1) {
            s  += __shfl_down(s, o);
            ss += __shfl_down(ss, o);
        }
        __shared__ float red[8];
        int w = t >> 6;
        if ((t & 63) == 0) { red[w] = s; red[4 + w] = ss; }
        __syncthreads();
        if (t == 0) {
            s  = red[0] + red[1] + red[2] + red[3];
            ss = red[4] + red[5] + red[6] + red[7];
            float mean = s * (1.0f / SP);
            float var  = (ss - s * mean) * (1.0f / (SP - 1));
            ws[WS_MEAN + bid] = mean;
            ws[WS_RSTD + bid] = rsqrtf(var + 1e-5f);
        }
    } else {
        int idx = (bid - N_B * CH) * 256 + t;        // 0..8191
        const float* p = style + (size_t)idx * 16;
        float s = 0.f;
        #pragma unroll
        for (int k = 0; k < 16; ++k) s += p[k];
        ws[WS_SD + idx] = s * (1.0f / 16.0f);
    }
}

// --------------------------- fused predictor: dw + pw_kn + pw_bias + fold ----
// block = (n, g). Produces per-(n,g): pwb[8] and packed fused weights
// W[j2][i]: d0=(k00,k01) d1=(k10,k11) d2=(k20,k21) d3=(k02,k12) d4=k22(f32), 8 dwords.
__global__ __launch_bounds__(256) void k_pred(const float* __restrict__ style,
                                              const float* __restrict__ dw_w,
                                              const float* __restrict__ dw_b,
                                              const float* __restrict__ pw_kn_w,
                                              const float* __restrict__ pw_kn_b,
                                              const float* __restrict__ pw_bias_w,
                                              const float* __restrict__ pw_bias_b,
                                              float* __restrict__ ws) {
    int n = blockIdx.x >> 6, g = blockIdx.x & 63, sg = g >> 3;
    __shared__ float s_st[64 * 16];
    __shared__ float s_sd[512];
    __shared__ float s_dwk[64 * 9];
    __shared__ float s_pwk[64];
    __shared__ float s_W[64 * 9];
    int t = threadIdx.x;

    for (int idx = t; idx < 1024; idx += 256)
        s_st[idx] = style[((size_t)n * CH + sg * 64) * 16 + idx];
    for (int idx = t; idx < 512; idx += 256)
        s_sd[idx] = ws[WS_SD + n * 512 + idx];
    __syncthreads();

    if (t < 192) {
        // depthwise predictor: oc_l = t&63, row ky = t>>6, 3 taps each
        int oc_l = t & 63, ky = t >> 6;
        int oc = g * 64 + oc_l;
        const float4* wp = (const float4*)(dw_w + (size_t)oc * 256);
        float a0 = 0.f, a1 = 0.f, a2 = 0.f;
        for (int ic = 0; ic < 64; ++ic) {
            float4 w = wp[ic];
            const float* sp = s_st + ic * 16 + ky * 4;
            a0 += w.x * sp[0] + w.y * sp[1] + w.z * sp[4] + w.w * sp[5];
            a1 += w.x * sp[1] + w.y * sp[2] + w.z * sp[5] + w.w * sp[6];
            a2 += w.x * sp[2] + w.y * sp[3] + w.z * sp[6] + w.w * sp[7];
        }
        float b = dw_b[oc];
        s_dwk[oc_l * 9 + ky * 3 + 0] = fmaxf(a0 + b, 0.f);
        s_dwk[oc_l * 9 + ky * 3 + 1] = fmaxf(a1 + b, 0.f);
        s_dwk[oc_l * 9 + ky * 3 + 2] = fmaxf(a2 + b, 0.f);
    } else {
        int L = t - 192;                       // lane 0..63 of wave 3
        // pointwise-kernel predictor (one 64-dot per L)
        {
            const float4* wp = (const float4*)(pw_kn_w + (size_t)(g * 64 + L) * 64);
            const float* sp = s_sd + sg * 64;
            float a = 0.f;
            #pragma unroll
            for (int k = 0; k < 16; ++k) {
                float4 w = wp[k];
                a += w.x * sp[k * 4] + w.y * sp[k * 4 + 1] + w.z * sp[k * 4 + 2] + w.w * sp[k * 4 + 3];
            }
            s_pwk[L] = fmaxf(a + pw_kn_b[g * 64 + L], 0.f);
        }
        // pointwise-bias predictor: 8 outputs x 8 lanes (64-chunk each)
        {
            int j2 = L >> 3, ch = L & 7;
            int c2 = g * 8 + j2;
            const float4* bp = (const float4*)(pw_bias_w + (size_t)c2 * 512 + ch * 64);
            const float* sq = s_sd + ch * 64;
            float s = 0.f;
            #pragma unroll
            for (int k = 0; k < 16; ++k) {
                float4 w = bp[k];
                s += w.x * sq[k * 4] + w.y * sq[k * 4 + 1] + w.z * sq[k * 4 + 2] + w.w * sq[k * 4 + 3];
            }
            s += __shfl_down(s, 4);
            s += __shfl_down(s, 2);
            s += __shfl_down(s, 1);
            if (ch == 0) ws[WS_PWB + n * 512 + c2] = fmaxf(s + pw_bias_b[c2], 0.f);
        }
    }
    __syncthreads();

    // fold pointwise into depthwise: W[j2][i][tap] = sum_j pwk[j2*8+j]*dwk[(j*8+i)][tap]
    for (int job = t; job < 576; job += 256) {
        int tap = job % 9, ji = job / 9;
        int j2 = ji >> 3, i = ji & 7;
        float a = 0.f;
        #pragma unroll
        for (int j = 0; j < 8; ++j)
            a += s_pwk[j2 * 8 + j] * s_dwk[(j * 8 + i) * 9 + tap];
        s_W[ji * 9 + tap] = a;
    }
    __syncthreads();

    // pack to f16 pairs
    unsigned* wout = (unsigned*)(ws + WS_W) + (size_t)(n * 64 + g) * 512;
    for (int job = t; job < 512; job += 256) {
        int ji = job >> 3, d2 = job & 7;
        const float* Wp = s_W + ji * 9;
        unsigned v = 0;
        if      (d2 == 0) v = pk16(Wp[0], Wp[1]);
        else if (d2 == 1) v = pk16(Wp[3], Wp[4]);
        else if (d2 == 2) v = pk16(Wp[6], Wp[7]);
        else if (d2 == 3) v = pk16(Wp[2], Wp[5]);
        else if (d2 == 4) { float f = Wp[8]; __builtin_memcpy(&v, &f, 4); }
        wout[job] = v;
    }
}

// ------------------------------------------------------- fused main op ----
// block = (n, group g, 16-row tile ty). LDS tile f16: position p = col p-1,
// row stride 72 (p=0..65 used). Reflect: pos0=col1, pos65=col62.
#define TST 72
__global__ __launch_bounds__(256, 5) void k_main(const float* __restrict__ content,
                                                 const float* __restrict__ ws,
                                                 float* __restrict__ out) {
    int bid = blockIdx.x;
    int ty = bid & 3, g = (bid >> 2) & 63, n = bid >> 8;
    __shared__ __align__(16) unsigned short cn[8][18][TST];
    __shared__ __align__(16) unsigned s_w[512];
    __shared__ float s_wb[8];
    __shared__ float s_ms[16];

    int t = threadIdx.x;
    {
        const float4* wsrc = (const float4*)(ws + WS_W) + (size_t)(n * 64 + g) * 128;
        if (t < 128) ((float4*)s_w)[t] = wsrc[t];
        if (t < 8) {
            s_wb[t]     = ws[WS_PWB + n * 512 + g * 8 + t];
            s_ms[t]     = ws[WS_MEAN + n * 512 + g * 8 + t];
            s_ms[8 + t] = ws[WS_RSTD + n * 512 + g * 8 + t];
        }
    }
    __syncthreads();

    // ---- stage: 144 (ch,row) segments, 16 lanes each ----
    int y0 = ty * 16;
    int q = t & 15, grp = t >> 4;
    const float* cbase = content + ((size_t)(n * CH + g * 8)) * SP;
    #pragma unroll 3
    for (int cc = 0; cc < 9; ++cc) {
        int rowid = cc * 16 + grp;            // 0..143
        int i = rowid / 18, r = rowid - i * 18;
        float sA = s_ms[8 + i];               // rstd
        float sB = -s_ms[i] * sA;             // -mean*rstd
        int gy = y0 + r - 1;
        gy = gy < 0 ? 1 : (gy > 63 ? 62 : gy);
        float4 v = *(const float4*)(cbase + (size_t)i * SP + gy * 64 + 4 * q);
        unsigned u0 = pk16(fmaf(v.x, sA, sB), fmaf(v.y, sA, sB));
        unsigned u1 = pk16(fmaf(v.z, sA, sB), fmaf(v.w, sA, sB));
        unsigned pu1 = __shfl_up(u1, 1);
        if (q == 0) pu1 = u0;                  // pos0 = reflect(col1)
        uint2 o;
        o.x = (pu1 >> 16) | (u0 << 16);        // positions 4q,4q+1
        o.y = (u0 >> 16) | (u1 << 16);         // positions 4q+2,4q+3
        *(uint2*)&cn[i][r][4 * q] = o;
        if (q == 15)                           // positions 64,65 = cols 63,62
            *(unsigned*)&cn[i][r][64] = (u1 >> 16) | (u1 << 16);
    }
    __syncthreads();

    // ---- compute: thread owns 4 px (row r_o, cols x0..x0+3) ----
    int r_o = t >> 4, k16 = t & 15, x0 = k16 << 2;
    float acc[8][4];
    #pragma unroll
    for (int j = 0; j < 8; ++j)
        #pragma unroll
        for (int p = 0; p < 4; ++p) acc[j][p] = 0.f;

    for (int i = 0; i < 8; ++i) {
        unsigned R0[3], R1[3], R2[3];
        #pragma unroll
        for (int ky = 0; ky < 3; ++ky) {
            const unsigned short* rp = &cn[i][r_o + ky][4 * k16];
            uint2 a = *(const uint2*)rp;               // positions x0..x0+3
            unsigned b = *(const unsigned*)(rp + 4);   // positions x0+4,x0+5
            R0[ky] = a.x; R1[ky] = a.y; R2[ky] = b;
        }
        unsigned pr[3][4];
        #pragma unroll
        for (int ky = 0; ky < 3; ++ky) {
            pr[ky][0] = R0[ky];
            pr[ky][1] = __builtin_amdgcn_alignbit(R1[ky], R0[ky], 16);
            pr[ky][2] = R1[ky];
            pr[ky][3] = __builtin_amdgcn_alignbit(R2[ky], R1[ky], 16);
        }
        unsigned cp[4];
        cp[0] = __builtin_amdgcn_perm(R1[1], R1[0], 0x05040100u);  // (lo,lo)
        cp[1] = __builtin_amdgcn_perm(R1[1], R1[0], 0x07060302u);  // (hi,hi)
        cp[2] = __builtin_amdgcn_perm(R2[1], R2[0], 0x05040100u);
        cp[3] = __builtin_amdgcn_perm(R2[1], R2[0], 0x07060302u);
        float sf[4] = { f16lo(R1[2]), f16hi(R1[2]), f16lo(R2[2]), f16hi(R2[2]) };
        #pragma unroll
        for (int j2 = 0; j2 < 8; ++j2) {
            const unsigned* wb = &s_w[(j2 * 8 + i) * 8];
            uint4 d = *(const uint4*)wb;
            float k22 = ((const float*)wb)[4];
            #pragma unroll
            for (int p = 0; p < 4; ++p) {
                float a = acc[j2][p];
                a = dot2(d.x, pr[0][p], a);
                a = dot2(d.y, pr[1][p], a);
                a = dot2(d.z, pr[2][p], a);
                a = dot2(d.w, cp[p], a);
                acc[j2][p] = fmaf(k22, sf[p], a);
            }
        }
    }

    // ---- bias + leaky(0.01) + cn add + NT store ----
    size_t obase = ((size_t)(n * CH + g * 8) * 64 + (y0 + r_o)) * 64 + x0;
    #pragma unroll
    for (int j2 = 0; j2 < 8; ++j2) {
        const unsigned short* rp = &cn[j2][r_o + 1][4 * k16];
        uint2 a = *(const uint2*)rp;
        unsigned b = *(const unsigned*)(rp + 4);
        float cv[4] = { f16hi(a.x), f16lo(a.y), f16hi(a.y), f16lo(b) };
        float bias = s_wb[j2];
        f32x4 o;
        #pragma unroll
        for (int p = 0; p < 4; ++p) {
            float v = acc[j2][p] + bias;
            v = v > 0.f ? v : 0.01f * v;
            o[p] = v + cv[p];
        }
        __builtin_nontemporal_store(o, (f32x4*)(out + obase + (size_t)j2 * SP));
    }
}

extern "C" void kernel_launch(void* const* d_in, const int* in_sizes, int n_in,
                              void* d_out, int out_size, void* d_ws, size_t ws_size,
                              hipStream_t stream) {
    const float* style     = (const float*)d_in[0];
    const float* content   = (const float*)d_in[1];
    const float* dw_w      = (const float*)d_in[2];
    const float* dw_b      = (const float*)d_in[3];
    const float* pw_kn_w   = (const float*)d_in[4];
    const float* pw_kn_b   = (const float*)d_in[5];
    const float* pw_bias_w = (const float*)d_in[6];
    const float* pw_bias_b = (const float*)d_in[7];
    float* out = (float*)d_out;
    float* ws  = (float*)d_ws;

    k_stats<<<dim3(N_B * CH + 32), dim3(256), 0, stream>>>(content, style, ws);
    k_pred <<<dim3(1024),          dim3(256), 0, stream>>>(style, dw_w, dw_b, pw_kn_w,
                                                           pw_kn_b, pw_bias_w, pw_bias_b, ws);
    k_main <<<dim3(4096),          dim3(256), 0, stream>>>(content, ws, out);
}